// Round 1
// baseline (314.809 us; speedup 1.0000x reference)
//
#include <hip/hip_runtime.h>
#include <hip/hip_bf16.h>

// BitNetAttention: B=2,S=2048,HID=1024,NH=16,HD=64
#define NB 2
#define NS 2048
#define NHID 1024
#define NHEAD 16
#define NHD 64
#define NTOK (NB*NS)        // 4096
#define WELEM (NHID*NHID)   // 1048576

typedef unsigned short u16;
typedef __attribute__((ext_vector_type(4))) float floatx4;
typedef __attribute__((ext_vector_type(8))) __bf16 bf16x8;
typedef __attribute__((ext_vector_type(8))) unsigned short ushort8;

__device__ __forceinline__ u16 f2bf(float f) {
  union { float f; unsigned u; } a; a.f = f;
  unsigned u = a.u;
  unsigned r = (u + 0x7fffu + ((u >> 16) & 1u)) >> 16;  // RNE
  return (u16)r;
}
__device__ __forceinline__ float bf2f(u16 s) {
  union { unsigned u; float f; } a; a.u = ((unsigned)s) << 16;
  return a.f;
}
__device__ __forceinline__ void gload16(const void* g, void* lds) {
  __builtin_amdgcn_global_load_lds(
      (const __attribute__((address_space(1))) unsigned int*)g,
      (__attribute__((address_space(3))) unsigned int*)lds, 16, 0, 0);
}

// ---------------- scale reduction (fp64 for boundary fidelity) --------------
__global__ void k_init(double* sums) { if (threadIdx.x < 4) sums[threadIdx.x] = 0.0; }

__global__ void k_abssum(const float* __restrict__ wq, const float* __restrict__ wk,
                         const float* __restrict__ wv, const float* __restrict__ wo,
                         double* __restrict__ sums) {
  const float* srcs[4] = {wq, wk, wv, wo};
  const float* w = srcs[blockIdx.y];
  int idx = (blockIdx.x * 256 + threadIdx.x) * 16;
  float s = 0.f;
#pragma unroll
  for (int j = 0; j < 4; j++) {
    float4 v = *(const float4*)(w + idx + j * 4);
    s += fabsf(v.x) + fabsf(v.y) + fabsf(v.z) + fabsf(v.w);
  }
#pragma unroll
  for (int off = 32; off; off >>= 1) s += __shfl_down(s, off);
  __shared__ float ps[4];
  if ((threadIdx.x & 63) == 0) ps[threadIdx.x >> 6] = s;
  __syncthreads();
  if (threadIdx.x == 0) atomicAdd(&sums[blockIdx.y], (double)(ps[0] + ps[1] + ps[2] + ps[3]));
}

__global__ void k_quant(const float* __restrict__ wq, const float* __restrict__ wk,
                        const float* __restrict__ wv, const float* __restrict__ wo,
                        const double* __restrict__ sums, u16* __restrict__ wt) {
  const float* srcs[4] = {wq, wk, wv, wo};
  const float* w = srcs[blockIdx.y];
  u16* dst = wt + blockIdx.y * WELEM;
  float s = (float)(sums[blockIdx.y] / (double)WELEM) + 1e-5f;
  int idx = (blockIdx.x * 256 + threadIdx.x) * 4;
  float4 v = *(const float4*)(w + idx);
  float f[4] = {v.x, v.y, v.z, v.w};
  union { u16 ss[4]; uint2 u; } O;
#pragma unroll
  for (int j = 0; j < 4; j++) {
    float q = rintf(f[j] / s);            // round-half-even, matches np.round
    q = fminf(1.f, fmaxf(-1.f, q));
    O.ss[j] = f2bf(q);                    // ternary exact in bf16
  }
  *(uint2*)(dst + idx) = O.u;
}

// ---------------- fp32 -> bf16 hi/lo split ---------------------------------
__global__ void k_split(const float* __restrict__ x, u16* __restrict__ hi, u16* __restrict__ lo) {
  int idx = (blockIdx.x * 256 + threadIdx.x) * 4;
  float4 v = *(const float4*)(x + idx);
  float f[4] = {v.x, v.y, v.z, v.w};
  union { u16 s[4]; uint2 u; } H, L;
#pragma unroll
  for (int j = 0; j < 4; j++) {
    u16 hb = f2bf(f[j]);
    H.s[j] = hb;
    L.s[j] = f2bf(f[j] - bf2f(hb));
  }
  *(uint2*)(hi + idx) = H.u;
  *(uint2*)(lo + idx) = L.u;
}

// ---------------- GEMM: C[m,o] = sum_k (Ahi+Alo)[m,k] * W[o,k] --------------
// MODE 0: z in {0,1,2} selects {q,k,v}; write hi/lo bf16 in [b,h,s,d] layout.
// MODE 1: write fp32 to outf[m*1024+o] (final projection with W_o).
template <int MODE>
__global__ __launch_bounds__(256) void k_gemm(
    const u16* __restrict__ Ahi, const u16* __restrict__ Alo,
    const u16* __restrict__ Wt, float* __restrict__ outf,
    u16* __restrict__ qh, u16* __restrict__ ql,
    u16* __restrict__ kh, u16* __restrict__ kl,
    u16* __restrict__ vh, u16* __restrict__ vl) {
  __shared__ __attribute__((aligned(16))) u16 At[128 * 32];
  __shared__ __attribute__((aligned(16))) u16 Bt[128 * 32];
  const int tid = threadIdx.x;
  const int wave = tid >> 6, lane = tid & 63;
  const int lr = lane & 15, lh = lane >> 4;
  const int bm = blockIdx.x, bn = blockIdx.y, z = blockIdx.z;
  const u16* W = Wt + (MODE == 0 ? z : 3) * WELEM;
  const int wr = wave >> 1, wc = wave & 1;

  floatx4 acc[4][4];
#pragma unroll
  for (int i = 0; i < 4; i++)
#pragma unroll
    for (int j = 0; j < 4; j++) acc[i][j] = (floatx4){0.f, 0.f, 0.f, 0.f};

  const int e0 = tid * 8;
  const int row0 = e0 >> 5, col0 = e0 & 31;

  for (int kt = 0; kt < 64; ++kt) {  // K_eff = 2048 = [hi | lo]
    const u16* Asrc = (kt < 32) ? Ahi : Alo;
    const int k0 = (kt & 31) * 32;
#pragma unroll
    for (int it = 0; it < 2; ++it) {
      int row = row0 + it * 64;
      gload16(Asrc + (bm * 128 + row) * 1024 + k0 + col0, (char*)At + it * 4096 + wave * 1024);
      gload16(W    + (bn * 128 + row) * 1024 + k0 + col0, (char*)Bt + it * 4096 + wave * 1024);
    }
    __syncthreads();
    bf16x8 af[4], bfr[4];
#pragma unroll
    for (int mi = 0; mi < 4; mi++)
      af[mi] = *(const bf16x8*)(At + (wr * 64 + mi * 16 + lr) * 32 + lh * 8);
#pragma unroll
    for (int ni = 0; ni < 4; ni++)
      bfr[ni] = *(const bf16x8*)(Bt + (wc * 64 + ni * 16 + lr) * 32 + lh * 8);
#pragma unroll
    for (int mi = 0; mi < 4; mi++)
#pragma unroll
      for (int ni = 0; ni < 4; ni++)
        acc[mi][ni] = __builtin_amdgcn_mfma_f32_16x16x32_bf16(af[mi], bfr[ni], acc[mi][ni], 0, 0, 0);
    __syncthreads();
  }

#pragma unroll
  for (int mi = 0; mi < 4; mi++)
#pragma unroll
    for (int ni = 0; ni < 4; ni++)
#pragma unroll
      for (int i = 0; i < 4; i++) {
        int row = bm * 128 + wr * 64 + mi * 16 + lh * 4 + i;  // token
        int col = bn * 128 + wc * 64 + ni * 16 + lr;          // out feature
        float v = acc[mi][ni][i];
        if (MODE == 1) {
          outf[row * 1024 + col] = v;
        } else {
          int b = row >> 11, s = row & 2047, hh = col >> 6, hd = col & 63;
          int dst = ((b * NHEAD + hh) * NS + s) * NHD + hd;
          u16 hb = f2bf(v);
          u16 lb = f2bf(v - bf2f(hb));
          u16 *dh, *dl;
          if (z == 0)      { dh = qh; dl = ql; }
          else if (z == 1) { dh = kh; dl = kl; }
          else             { dh = vh; dl = vl; }
          dh[dst] = hb; dl[dst] = lb;
        }
      }
}

// ---------------- RoPE (in-place on hi/lo pairs), precise trig --------------
__global__ void k_rope(const int* __restrict__ pos_ids,
                       u16* __restrict__ qh, u16* __restrict__ ql,
                       u16* __restrict__ kh, u16* __restrict__ kl) {
  int gid = blockIdx.x * 256 + threadIdx.x;
  int row = gid >> 5, d = gid & 31;          // row in [0, B*NH*S)
  int bh = row >> 11, s = row & 2047, b = bh >> 4;
  int pos = pos_ids[b * NS + s];
  float inv = 1.0f / powf(10000.0f, (float)(2 * d) / 64.0f);
  float fr = (float)pos * inv;
  float c = cosf(fr), sn = sinf(fr);
  int off = row * 64 + d;
  {
    float x1 = bf2f(qh[off]) + bf2f(ql[off]);
    float x2 = bf2f(qh[off + 32]) + bf2f(ql[off + 32]);
    float n1 = x1 * c - x2 * sn;
    float n2 = x2 * c + x1 * sn;
    u16 h1 = f2bf(n1); qh[off] = h1;       ql[off] = f2bf(n1 - bf2f(h1));
    u16 h2 = f2bf(n2); qh[off + 32] = h2;  ql[off + 32] = f2bf(n2 - bf2f(h2));
  }
  {
    float x1 = bf2f(kh[off]) + bf2f(kl[off]);
    float x2 = bf2f(kh[off + 32]) + bf2f(kl[off + 32]);
    float n1 = x1 * c - x2 * sn;
    float n2 = x2 * c + x1 * sn;
    u16 h1 = f2bf(n1); kh[off] = h1;       kl[off] = f2bf(n1 - bf2f(h1));
    u16 h2 = f2bf(n2); kh[off + 32] = h2;  kl[off + 32] = f2bf(n2 - bf2f(h2));
  }
}

// ---------------- flash attention, 4 waves x 32 q-rows, KBLK=64 -------------
__global__ __launch_bounds__(256) void k_attn(
    const u16* __restrict__ qh, const u16* __restrict__ ql,
    const u16* __restrict__ kh, const u16* __restrict__ kl,
    const u16* __restrict__ vh, float* __restrict__ ao) {
  __shared__ __attribute__((aligned(16))) u16 KhT[64 * 64];
  __shared__ __attribute__((aligned(16))) u16 KlT[64 * 64];
  __shared__ __attribute__((aligned(16))) u16 Vt[64 * 64];   // transposed [d][key]
  __shared__ __attribute__((aligned(16))) u16 Pl[4 * 32 * 64];
  const int tid = threadIdx.x, wave = tid >> 6, lane = tid & 63;
  const int lr = lane & 15, lh = lane >> 4;
  const int qt = blockIdx.x, bh = blockIdx.y;
  const int b = bh >> 4, hco = (bh & 15) * NHD;
  const int base = bh * (NS * NHD);
  const int qbase = qt * 128 + wave * 32;

  bf16x8 qfh[2][2], qfl[2][2];
#pragma unroll
  for (int rf = 0; rf < 2; rf++)
#pragma unroll
    for (int ks = 0; ks < 2; ks++) {
      int off = base + (qbase + rf * 16 + lr) * NHD + ks * 32 + lh * 8;
      qfh[rf][ks] = *(const bf16x8*)(qh + off);
      qfl[rf][ks] = *(const bf16x8*)(ql + off);
    }
  floatx4 acco[2][4];
  float m_r[2][4], l_r[2][4];
#pragma unroll
  for (int rf = 0; rf < 2; rf++) {
#pragma unroll
    for (int df = 0; df < 4; df++) acco[rf][df] = (floatx4){0.f, 0.f, 0.f, 0.f};
#pragma unroll
    for (int i = 0; i < 4; i++) { m_r[rf][i] = -1e30f; l_r[rf][i] = 0.f; }
  }
  char* Pw = (char*)Pl + wave * 4096;

  for (int kt = 0; kt < 32; ++kt) {
    const int key0 = kt * 64;
    // K tiles: linear LDS dest, pre-swizzled global source (involution L ^= ((L>>7)&7)<<4)
    const char* khg = (const char*)(kh + base + key0 * NHD);
    const char* klg = (const char*)(kl + base + key0 * NHD);
#pragma unroll
    for (int it = 0; it < 2; ++it) {
      int L = it * 4096 + tid * 16;
      int g = L ^ (((L >> 7) & 7) << 4);
      gload16(khg + g, (char*)KhT + it * 4096 + wave * 1024);
      gload16(klg + g, (char*)KlT + it * 4096 + wave * 1024);
    }
    {  // V transposed + swizzled, reg-staged
      int key = tid >> 2, d0 = (tid & 3) * 16;
      const u16* vp = vh + base + (key0 + key) * NHD + d0;
      ushort8 v0 = *(const ushort8*)vp;
      ushort8 v1 = *(const ushort8*)(vp + 8);
#pragma unroll
      for (int j = 0; j < 8; j++) {
        int d = d0 + j;
        *(u16*)((char*)Vt + d * 128 + ((key * 2) ^ ((d & 7) << 4))) = v0[j];
      }
#pragma unroll
      for (int j = 0; j < 8; j++) {
        int d = d0 + 8 + j;
        *(u16*)((char*)Vt + d * 128 + ((key * 2) ^ ((d & 7) << 4))) = v1[j];
      }
    }
    __syncthreads();

    // S = Q K^T (3-way hi/lo split)
    floatx4 sac[2][4];
#pragma unroll
    for (int rf = 0; rf < 2; rf++)
#pragma unroll
      for (int cf = 0; cf < 4; cf++) sac[rf][cf] = (floatx4){0.f, 0.f, 0.f, 0.f};
#pragma unroll
    for (int cf = 0; cf < 4; cf++) {
      const int key = cf * 16 + lr;
      const int swz = (key & 7) << 4;
#pragma unroll
      for (int ks = 0; ks < 2; ks++) {
        int byteK = key * 128 + ((ks * 64 + lh * 16) ^ swz);
        bf16x8 bh_ = *(const bf16x8*)((const char*)KhT + byteK);
        bf16x8 bl_ = *(const bf16x8*)((const char*)KlT + byteK);
#pragma unroll
        for (int rf = 0; rf < 2; rf++) {
          sac[rf][cf] = __builtin_amdgcn_mfma_f32_16x16x32_bf16(qfh[rf][ks], bh_, sac[rf][cf], 0, 0, 0);
          sac[rf][cf] = __builtin_amdgcn_mfma_f32_16x16x32_bf16(qfh[rf][ks], bl_, sac[rf][cf], 0, 0, 0);
          sac[rf][cf] = __builtin_amdgcn_mfma_f32_16x16x32_bf16(qfl[rf][ks], bh_, sac[rf][cf], 0, 0, 0);
        }
      }
    }

    // online softmax (rows live in 16-lane groups; shfl_xor reduce)
#pragma unroll
    for (int rf = 0; rf < 2; rf++) {
      float al[4];
#pragma unroll
      for (int i = 0; i < 4; i++) {
        float mt = fmaxf(fmaxf(sac[rf][0][i], sac[rf][1][i]),
                         fmaxf(sac[rf][2][i], sac[rf][3][i])) * 0.125f;
#pragma unroll
        for (int off = 1; off < 16; off <<= 1) mt = fmaxf(mt, __shfl_xor(mt, off));
        float mn = fmaxf(m_r[rf][i], mt);
        al[i] = __expf(m_r[rf][i] - mn);
        float rs = 0.f;
#pragma unroll
        for (int cf = 0; cf < 4; cf++) {
          float pv = __expf(sac[rf][cf][i] * 0.125f - mn);
          sac[rf][cf][i] = pv;
          rs += pv;
        }
#pragma unroll
        for (int off = 1; off < 16; off <<= 1) rs += __shfl_xor(rs, off);
        l_r[rf][i] = l_r[rf][i] * al[i] + rs;
        m_r[rf][i] = mn;
      }
#pragma unroll
      for (int df = 0; df < 4; df++) {
        floatx4 t = acco[rf][df];
#pragma unroll
        for (int i = 0; i < 4; i++) t[i] *= al[i];
        acco[rf][df] = t;
      }
#pragma unroll
      for (int cf = 0; cf < 4; cf++)
#pragma unroll
        for (int i = 0; i < 4; i++) {
          int prow = rf * 16 + lh * 4 + i;
          int pcol = cf * 16 + lr;
          *(u16*)(Pw + prow * 128 + ((pcol * 2) ^ ((prow & 7) << 4))) = f2bf(sac[rf][cf][i]);
        }
    }

    // O += P V
#pragma unroll
    for (int ks = 0; ks < 2; ks++) {
      bf16x8 vf[4];
#pragma unroll
      for (int df = 0; df < 4; df++) {
        int d = df * 16 + lr;
        vf[df] = *(const bf16x8*)((const char*)Vt + d * 128 + (((ks * 32 + lh * 8) * 2) ^ ((d & 7) << 4)));
      }
#pragma unroll
      for (int rf = 0; rf < 2; rf++) {
        int prow = rf * 16 + lr;
        bf16x8 pf = *(const bf16x8*)((const char*)Pw + prow * 128 + (((ks * 32 + lh * 8) * 2) ^ ((prow & 7) << 4)));
#pragma unroll
        for (int df = 0; df < 4; df++)
          acco[rf][df] = __builtin_amdgcn_mfma_f32_16x16x32_bf16(pf, vf[df], acco[rf][df], 0, 0, 0);
      }
    }
    __syncthreads();
  }

#pragma unroll
  for (int rf = 0; rf < 2; rf++)
#pragma unroll
    for (int df = 0; df < 4; df++)
#pragma unroll
      for (int i = 0; i < 4; i++) {
        int row = qbase + rf * 16 + lh * 4 + i;
        int col = hco + df * 16 + lr;
        ao[(b * NS + row) * NHID + col] = acco[rf][df][i] / l_r[rf][i];
      }
}

__global__ void k_scale(const double* __restrict__ sums, const float* __restrict__ hss,
                        float* __restrict__ out) {
  if (threadIdx.x == 0) {
    float sv = (float)(sums[2] / (double)WELEM) + 1e-5f;
    float so = (float)(sums[3] / (double)WELEM) + 1e-5f;
    out[NTOK * NHID] = hss[0] * sv * so;
  }
}

extern "C" void kernel_launch(void* const* d_in, const int* in_sizes, int n_in,
                              void* d_out, int out_size, void* d_ws, size_t ws_size,
                              hipStream_t stream) {
  const float* x   = (const float*)d_in[0];
  const float* hss = (const float*)d_in[1];
  const int*   pos = (const int*)d_in[2];
  const float* wq  = (const float*)d_in[3];
  const float* wk  = (const float*)d_in[4];
  const float* wv  = (const float*)d_in[5];
  const float* wo  = (const float*)d_in[6];
  float* out = (float*)d_out;
  char* ws = (char*)d_ws;
  const size_t MB = 1u << 20;
  u16* wt = (u16*)(ws);              // 4 ternary matrices, 8MB
  u16* xh = (u16*)(ws + 8 * MB);
  u16* xl = (u16*)(ws + 16 * MB);
  u16* qh = (u16*)(ws + 24 * MB);
  u16* ql = (u16*)(ws + 32 * MB);
  u16* kh = (u16*)(ws + 40 * MB);
  u16* kl = (u16*)(ws + 48 * MB);
  u16* vh = (u16*)(ws + 56 * MB);
  u16* vl = (u16*)(ws + 64 * MB);
  float* ao = (float*)(ws + 72 * MB);  // 16MB
  double* sums = (double*)(ws + 88 * MB);
  u16* aoh = xh;  // x no longer needed after QKV proj
  u16* aol = xl;

  k_init<<<1, 64, 0, stream>>>(sums);
  k_abssum<<<dim3(256, 4), 256, 0, stream>>>(wq, wk, wv, wo, sums);
  k_quant<<<dim3(1024, 4), 256, 0, stream>>>(wq, wk, wv, wo, sums, wt);
  k_split<<<4096, 256, 0, stream>>>(x, xh, xl);
  k_gemm<0><<<dim3(32, 8, 3), 256, 0, stream>>>(xh, xl, wt, nullptr, qh, ql, kh, kl, vh, vl);
  k_rope<<<8192, 256, 0, stream>>>(pos, qh, ql, kh, kl);
  k_attn<<<dim3(16, 32), 256, 0, stream>>>(qh, ql, kh, kl, vh, ao);
  k_split<<<4096, 256, 0, stream>>>(ao, aoh, aol);
  k_gemm<1><<<dim3(32, 8, 1), 256, 0, stream>>>(aoh, aol, wt, out,
                                                nullptr, nullptr, nullptr, nullptr, nullptr, nullptr);
  k_scale<<<1, 64, 0, stream>>>(sums, hss, out);
}